// Round 1
// baseline (3186.583 us; speedup 1.0000x reference)
//
#include <hip/hip_runtime.h>

// Problem constants (from reference)
#define BB 16384   // batch rows
#define DIN 1024   // encoder input dim
#define CB 512     // codebook dim
#define KC 1024    // codewords per layer
#define NL 4       // layers

// ---------------------------------------------------------------------------
// cnorm[l*KC + k] = ||codebooks[l][k]||^2 in fp64 (one wave per codeword row)
// ---------------------------------------------------------------------------
__global__ __launch_bounds__(256) void cnorm_kernel(
    const float* __restrict__ cbs, double* __restrict__ cnorm) {
  int gw = (blockIdx.x * blockDim.x + threadIdx.x) >> 6;
  int lane = threadIdx.x & 63;
  if (gw >= NL * KC) return;
  const float* row = cbs + (size_t)gw * CB;
  double s = 0.0;
  for (int i = lane; i < CB; i += 64) {
    double v = (double)row[i];
    s += v * v;
  }
#pragma unroll
  for (int off = 32; off > 0; off >>= 1)
    s += __shfl_down(s, off, 64);
  if (lane == 0) cnorm[gw] = s;
}

// ---------------------------------------------------------------------------
// Encoder GEMM: R[16384,512] = X[16384,1024] @ W[1024,512] + b
// 64x64 tile, BK=16, 256 threads, 4x4 per thread, fp64 accumulation.
// ---------------------------------------------------------------------------
__global__ __launch_bounds__(256) void enc_gemm(
    const float* __restrict__ X, const float* __restrict__ W,
    const float* __restrict__ bias, float* __restrict__ R) {
  __shared__ float As[16][64];  // As[k][m]
  __shared__ float Bs[16][64];  // Bs[k][n]
  int tid = threadIdx.x;
  int tx = tid & 15, ty = tid >> 4;
  int row0 = blockIdx.y * 64, col0 = blockIdx.x * 64;

  double acc[4][4] = {};
  for (int k0 = 0; k0 < DIN; k0 += 16) {
    // stage A tile (64 rows x 16 k), float4 per thread, stored transposed
    {
      int r = tid >> 2, kk = (tid & 3) << 2;
      float4 a = *(const float4*)(X + (size_t)(row0 + r) * DIN + k0 + kk);
      As[kk + 0][r] = a.x; As[kk + 1][r] = a.y;
      As[kk + 2][r] = a.z; As[kk + 3][r] = a.w;
    }
    // stage B tile (16 k x 64 cols), float4 per thread
    {
      int kk = tid >> 4, c = (tid & 15) << 2;
      float4 b = *(const float4*)(W + (size_t)(k0 + kk) * CB + col0 + c);
      *(float4*)&Bs[kk][c] = b;
    }
    __syncthreads();
#pragma unroll
    for (int kk = 0; kk < 16; ++kk) {
      float4 av = *(const float4*)&As[kk][ty << 2];
      float4 bv = *(const float4*)&Bs[kk][tx << 2];
      double a[4] = {(double)av.x, (double)av.y, (double)av.z, (double)av.w};
      double b[4] = {(double)bv.x, (double)bv.y, (double)bv.z, (double)bv.w};
#pragma unroll
      for (int i = 0; i < 4; ++i)
#pragma unroll
        for (int j = 0; j < 4; ++j)
          acc[i][j] += a[i] * b[j];
    }
    __syncthreads();
  }
#pragma unroll
  for (int i = 0; i < 4; ++i) {
#pragma unroll
    for (int j = 0; j < 4; ++j) {
      int r = row0 + (ty << 2) + i, c = col0 + (tx << 2) + j;
      R[(size_t)r * CB + c] = (float)(acc[i][j] + (double)bias[c]);
    }
  }
}

// ---------------------------------------------------------------------------
// One VQ layer: for each row, argmin_k (||c_k||^2 - 2 r.c_k), write id,
// update residual in place. Block owns 64 rows; loops over all 1024 cols.
// fp64 accumulation + fp64 score compare (argmin must match hi-prec ref).
// ---------------------------------------------------------------------------
__global__ __launch_bounds__(256) void vq_layer(
    const float* __restrict__ cb,      // this layer's codebook [KC][CB]
    const double* __restrict__ cnorm,  // this layer's [KC]
    float* __restrict__ R,             // residual [BB][CB], updated in place
    float* __restrict__ idsF,          // ids as float, [BB][NL]
    int layer) {
  __shared__ float As[16][64];
  __shared__ float Bs[16][64];
  __shared__ double redMin[64][17];
  __shared__ int redIdx[64][17];
  __shared__ int bestIdx[64];

  int tid = threadIdx.x;
  int tx = tid & 15, ty = tid >> 4;
  int row0 = blockIdx.x * 64;

  double runMin[4];
  int runIdx[4];
#pragma unroll
  for (int i = 0; i < 4; ++i) { runMin[i] = 1e300; runIdx[i] = 0; }

  for (int col0 = 0; col0 < KC; col0 += 64) {
    double acc[4][4] = {};
    for (int k0 = 0; k0 < CB; k0 += 16) {
      {
        int r = tid >> 2, kk = (tid & 3) << 2;
        float4 a = *(const float4*)(R + (size_t)(row0 + r) * CB + k0 + kk);
        As[kk + 0][r] = a.x; As[kk + 1][r] = a.y;
        As[kk + 2][r] = a.z; As[kk + 3][r] = a.w;
      }
      {
        // Bs[kk][n] = cb[col0+n][k0+kk]  (transposed load)
        int n = tid >> 2, kk = (tid & 3) << 2;
        float4 b = *(const float4*)(cb + (size_t)(col0 + n) * CB + k0 + kk);
        Bs[kk + 0][n] = b.x; Bs[kk + 1][n] = b.y;
        Bs[kk + 2][n] = b.z; Bs[kk + 3][n] = b.w;
      }
      __syncthreads();
#pragma unroll
      for (int kk = 0; kk < 16; ++kk) {
        float4 av = *(const float4*)&As[kk][ty << 2];
        float4 bv = *(const float4*)&Bs[kk][tx << 2];
        double a[4] = {(double)av.x, (double)av.y, (double)av.z, (double)av.w};
        double b[4] = {(double)bv.x, (double)bv.y, (double)bv.z, (double)bv.w};
#pragma unroll
        for (int i = 0; i < 4; ++i)
#pragma unroll
          for (int j = 0; j < 4; ++j)
            acc[i][j] += a[i] * b[j];
      }
      __syncthreads();
    }
    // score and running argmin (cols ascending -> first-occurrence within thread)
#pragma unroll
    for (int j = 0; j < 4; ++j) {
      int col = col0 + (tx << 2) + j;
      double cn = cnorm[col];
#pragma unroll
      for (int i = 0; i < 4; ++i) {
        double s = cn - 2.0 * acc[i][j];
        if (s < runMin[i]) { runMin[i] = s; runIdx[i] = col; }
      }
    }
  }

  // cross-thread reduce: 16 threads (tx) share each row group ty*4+i
#pragma unroll
  for (int i = 0; i < 4; ++i) {
    redMin[(ty << 2) + i][tx] = runMin[i];
    redIdx[(ty << 2) + i][tx] = runIdx[i];
  }
  __syncthreads();
  if (tid < 64) {
    double m = redMin[tid][0];
    int bi = redIdx[tid][0];
    for (int t = 1; t < 16; ++t) {
      double v = redMin[tid][t];
      int ix = redIdx[tid][t];
      if (v < m || (v == m && ix < bi)) { m = v; bi = ix; }
    }
    bestIdx[tid] = bi;
    idsF[(size_t)(row0 + tid) * NL + layer] = (float)bi;
  }
  __syncthreads();

  // residual update: R[row] -= cb[best[row]]
  for (int e = tid; e < 64 * CB; e += 256) {
    int r = e >> 9, d = e & (CB - 1);
    R[(size_t)(row0 + r) * CB + d] -= cb[(size_t)bestIdx[r] * CB + d];
  }
}

// ---------------------------------------------------------------------------
// recon[b][j] = dec_b[j] + sum_l ids[b][l] * dec_W[l][j]
// ---------------------------------------------------------------------------
__global__ __launch_bounds__(256) void recon_kernel(
    const float* __restrict__ idsF, const float* __restrict__ decW,
    const float* __restrict__ decb, float* __restrict__ recon) {
  int g = blockIdx.x * 256 + threadIdx.x;
  int b = g >> 9, j = g & (CB - 1);
  float s = decb[j];
#pragma unroll
  for (int l = 0; l < NL; ++l)
    s += idsF[(size_t)b * NL + l] * decW[l * CB + j];
  recon[g] = s;
}

extern "C" void kernel_launch(void* const* d_in, const int* in_sizes, int n_in,
                              void* d_out, int out_size, void* d_ws, size_t ws_size,
                              hipStream_t stream) {
  const float* X    = (const float*)d_in[0];  // [16384,1024]
  const float* encW = (const float*)d_in[1];  // [1024,512]
  const float* encb = (const float*)d_in[2];  // [512]
  const float* cbs  = (const float*)d_in[3];  // [4,1024,512]
  const float* decW = (const float*)d_in[4];  // [4,512]
  const float* decb = (const float*)d_in[5];  // [512]

  float* out = (float*)d_out;
  float* recon = out;                          // [16384*512]
  float* idsF = out + (size_t)BB * CB;         // [16384*4] ids stored as float

  float* R = (float*)d_ws;                     // residual, 32 MB
  double* cnorm = (double*)((char*)d_ws + (size_t)BB * CB * sizeof(float)); // 32 KB

  cnorm_kernel<<<(NL * KC) / 4, 256, 0, stream>>>(cbs, cnorm);
  enc_gemm<<<dim3(CB / 64, BB / 64), 256, 0, stream>>>(X, encW, encb, R);
  for (int l = 0; l < NL; ++l)
    vq_layer<<<BB / 64, 256, 0, stream>>>(cbs + (size_t)l * KC * CB,
                                          cnorm + (size_t)l * KC, R, idsF, l);
  recon_kernel<<<(BB * CB) / 256, 256, 0, stream>>>(idsF, decW, decb, recon);
}

// Round 2
// 1863.433 us; speedup vs baseline: 1.7101x; 1.7101x over previous
//
#include <hip/hip_runtime.h>
#include <float.h>
#include <limits.h>

// Problem constants (from reference)
#define BB 16384   // batch rows
#define DIN 1024   // encoder input dim
#define CB 512     // codebook dim
#define KC 1024    // codewords per layer
#define NL 4       // layers

// Stage-2 refine margin: must exceed worst-case fp32 distance-GEMM error
// (<= eps * 512 * max|partial| + cnorm rounding ~ 8e-3). 0.05 gives 6x slack.
#define DELTA 0.05f

// ---------------------------------------------------------------------------
// cnorm[l*KC+k] = ||codebooks[l][k]||^2, fp64 (for refine) + fp32 (for stage1)
// ---------------------------------------------------------------------------
__global__ __launch_bounds__(256) void cnorm_kernel(
    const float* __restrict__ cbs, double* __restrict__ cnorm,
    float* __restrict__ cnormF) {
  int gw = (blockIdx.x * blockDim.x + threadIdx.x) >> 6;
  int lane = threadIdx.x & 63;
  if (gw >= NL * KC) return;
  const float* row = cbs + (size_t)gw * CB;
  double s = 0.0;
  for (int i = lane; i < CB; i += 64) {
    double v = (double)row[i];
    s += v * v;
  }
#pragma unroll
  for (int off = 32; off > 0; off >>= 1)
    s += __shfl_down(s, off, 64);
  if (lane == 0) { cnorm[gw] = s; cnormF[gw] = (float)s; }
}

// ---------------------------------------------------------------------------
// Encoder GEMM: R[16384,512] = X[16384,1024] @ W[1024,512] + b
// fp64 accumulation (at the 78.6 TF fp64 roofline; R fidelity gates flips).
// ---------------------------------------------------------------------------
__global__ __launch_bounds__(256) void enc_gemm(
    const float* __restrict__ X, const float* __restrict__ W,
    const float* __restrict__ bias, float* __restrict__ R) {
  __shared__ float As[16][64];  // As[k][m]
  __shared__ float Bs[16][64];  // Bs[k][n]
  int tid = threadIdx.x;
  int tx = tid & 15, ty = tid >> 4;
  int row0 = blockIdx.y * 64, col0 = blockIdx.x * 64;

  double acc[4][4] = {};
  for (int k0 = 0; k0 < DIN; k0 += 16) {
    {
      int r = tid >> 2, kk = (tid & 3) << 2;
      float4 a = *(const float4*)(X + (size_t)(row0 + r) * DIN + k0 + kk);
      As[kk + 0][r] = a.x; As[kk + 1][r] = a.y;
      As[kk + 2][r] = a.z; As[kk + 3][r] = a.w;
    }
    {
      int kk = tid >> 4, c = (tid & 15) << 2;
      float4 b = *(const float4*)(W + (size_t)(k0 + kk) * CB + col0 + c);
      *(float4*)&Bs[kk][c] = b;
    }
    __syncthreads();
#pragma unroll
    for (int kk = 0; kk < 16; ++kk) {
      float4 av = *(const float4*)&As[kk][ty << 2];
      float4 bv = *(const float4*)&Bs[kk][tx << 2];
      double a[4] = {(double)av.x, (double)av.y, (double)av.z, (double)av.w};
      double b[4] = {(double)bv.x, (double)bv.y, (double)bv.z, (double)bv.w};
#pragma unroll
      for (int i = 0; i < 4; ++i)
#pragma unroll
        for (int j = 0; j < 4; ++j)
          acc[i][j] += a[i] * b[j];
    }
    __syncthreads();
  }
#pragma unroll
  for (int i = 0; i < 4; ++i) {
#pragma unroll
    for (int j = 0; j < 4; ++j) {
      int r = row0 + (ty << 2) + i, c = col0 + (tx << 2) + j;
      R[(size_t)r * CB + c] = (float)(acc[i][j] + (double)bias[c]);
    }
  }
}

// ---------------------------------------------------------------------------
// Stage 1: fp32 distance GEMM over a 256-codeword chunk; per-row top-2
// candidates (value+index) written to cand[row*4+chunk].
// grid = 1024 blocks (256 row-tiles x 4 chunks) -> 4 blocks/CU.
// ---------------------------------------------------------------------------
__global__ __launch_bounds__(256) void vq_stage1(
    const float* __restrict__ cb,      // layer codebook [KC][CB]
    const float* __restrict__ cnormF,  // fp32 ||c||^2 for this layer [KC]
    const float* __restrict__ R,       // residual [BB][CB]
    float4* __restrict__ cand) {       // [BB*4]: {v1, i1, v2, i2}
  __shared__ float As[16][64];
  __shared__ float Bs[16][64];
  __shared__ float4 red[64][17];       // per (rowInTile, tx) top-2, padded

  int tid = threadIdx.x;
  int tx = tid & 15, ty = tid >> 4;
  int rowBlk = blockIdx.x >> 2;
  int chunk = blockIdx.x & 3;
  int row0 = rowBlk * 64;
  int colBase = chunk * 256;

  float m1[4], m2[4];
  int i1[4], i2[4];
#pragma unroll
  for (int i = 0; i < 4; ++i) {
    m1[i] = FLT_MAX; m2[i] = FLT_MAX; i1[i] = INT_MAX; i2[i] = INT_MAX;
  }

  for (int cc = 0; cc < 4; ++cc) {
    int col0 = colBase + cc * 64;
    float acc[4][4] = {};
    for (int k0 = 0; k0 < CB; k0 += 16) {
      {
        int r = tid >> 2, kk = (tid & 3) << 2;
        float4 a = *(const float4*)(R + (size_t)(row0 + r) * CB + k0 + kk);
        As[kk + 0][r] = a.x; As[kk + 1][r] = a.y;
        As[kk + 2][r] = a.z; As[kk + 3][r] = a.w;
      }
      {
        int n = tid >> 2, kk = (tid & 3) << 2;
        float4 b = *(const float4*)(cb + (size_t)(col0 + n) * CB + k0 + kk);
        Bs[kk + 0][n] = b.x; Bs[kk + 1][n] = b.y;
        Bs[kk + 2][n] = b.z; Bs[kk + 3][n] = b.w;
      }
      __syncthreads();
#pragma unroll
      for (int kk = 0; kk < 16; ++kk) {
        float4 av = *(const float4*)&As[kk][ty << 2];
        float4 bv = *(const float4*)&Bs[kk][tx << 2];
        float a[4] = {av.x, av.y, av.z, av.w};
        float b[4] = {bv.x, bv.y, bv.z, bv.w};
#pragma unroll
        for (int i = 0; i < 4; ++i)
#pragma unroll
          for (int j = 0; j < 4; ++j)
            acc[i][j] += a[i] * b[j];
      }
      __syncthreads();
    }
    // score + per-thread top-2 (cols ascending -> first-occurrence tie-break)
#pragma unroll
    for (int j = 0; j < 4; ++j) {
      int col = col0 + (tx << 2) + j;
      float cn = cnormF[col];
#pragma unroll
      for (int i = 0; i < 4; ++i) {
        float s = cn - 2.0f * acc[i][j];
        if (s < m1[i] || (s == m1[i] && col < i1[i])) {
          m2[i] = m1[i]; i2[i] = i1[i];
          m1[i] = s; i1[i] = col;
        } else if (s < m2[i] || (s == m2[i] && col < i2[i])) {
          m2[i] = s; i2[i] = col;
        }
      }
    }
  }

#pragma unroll
  for (int i = 0; i < 4; ++i)
    red[(ty << 2) + i][tx] =
        make_float4(m1[i], __int_as_float(i1[i]), m2[i], __int_as_float(i2[i]));
  __syncthreads();

  if (tid < 64) {
    float M1 = FLT_MAX, M2 = FLT_MAX;
    int I1 = INT_MAX, I2 = INT_MAX;
    for (int t = 0; t < 16; ++t) {
      float4 e = red[tid][t];
      float v[2] = {e.x, e.z};
      int ix[2] = {__float_as_int(e.y), __float_as_int(e.w)};
#pragma unroll
      for (int p = 0; p < 2; ++p) {
        if (v[p] < M1 || (v[p] == M1 && ix[p] < I1)) {
          M2 = M1; I2 = I1; M1 = v[p]; I1 = ix[p];
        } else if (v[p] < M2 || (v[p] == M2 && ix[p] < I2)) {
          M2 = v[p]; I2 = ix[p];
        }
      }
    }
    cand[(size_t)(row0 + tid) * 4 + chunk] =
        make_float4(M1, __int_as_float(I1), M2, __int_as_float(I2));
  }
}

// ---------------------------------------------------------------------------
// Stage 2: combine chunk candidates; fp64-refine rows with near-ties
// (d < min + DELTA); write id; update residual in place.
// ---------------------------------------------------------------------------
__global__ __launch_bounds__(256) void vq_refine(
    const float* __restrict__ cb, const double* __restrict__ cnorm,
    const float4* __restrict__ cand, float* __restrict__ R,
    float* __restrict__ idsF, int layer) {
  __shared__ int sIdx[64][8];
  __shared__ int sCnt[64];
  __shared__ int sBest[64];

  int tid = threadIdx.x;
  int row0 = blockIdx.x * 64;

  if (tid < 64) {
    int row = row0 + tid;
    float v[8]; int ix[8];
#pragma unroll
    for (int c = 0; c < 4; ++c) {
      float4 e = cand[(size_t)row * 4 + c];
      v[2 * c] = e.x;     ix[2 * c] = __float_as_int(e.y);
      v[2 * c + 1] = e.z; ix[2 * c + 1] = __float_as_int(e.w);
    }
    float M = FLT_MAX; int I = INT_MAX;
#pragma unroll
    for (int p = 0; p < 8; ++p)
      if (v[p] < M || (v[p] == M && ix[p] < I)) { M = v[p]; I = ix[p]; }
    int cnt = 0;
#pragma unroll
    for (int p = 0; p < 8; ++p)
      if (v[p] < M + DELTA) sIdx[tid][cnt++] = ix[p];
    sCnt[tid] = cnt;
    sBest[tid] = I;  // final answer unless cnt >= 2
  }
  __syncthreads();

  // fp64 refine for near-tie rows (rare): wave w owns rows [w*16, w*16+16)
  int wave = tid >> 6, lane = tid & 63;
  for (int r = wave * 16; r < wave * 16 + 16; ++r) {
    int cnt = sCnt[r];
    if (cnt < 2) continue;
    double bestD = 1e300; int bestI = INT_MAX;
    const float* rrow = R + (size_t)(row0 + r) * CB;
    for (int c = 0; c < cnt; ++c) {
      int idx = sIdx[r][c];
      const float* crow = cb + (size_t)idx * CB;
      double s = 0.0;
      for (int e = lane; e < CB; e += 64)
        s += (double)rrow[e] * (double)crow[e];
#pragma unroll
      for (int off = 32; off > 0; off >>= 1)
        s += __shfl_xor(s, off, 64);
      double d = cnorm[idx] - 2.0 * s;
      if (d < bestD || (d == bestD && idx < bestI)) { bestD = d; bestI = idx; }
    }
    if (lane == 0) sBest[r] = bestI;
  }
  __syncthreads();

  if (tid < 64)
    idsF[(size_t)(row0 + tid) * NL + layer] = (float)sBest[tid];

  for (int e = tid; e < 64 * CB; e += 256) {
    int r = e >> 9, d = e & (CB - 1);
    R[(size_t)(row0 + r) * CB + d] -= cb[(size_t)sBest[r] * CB + d];
  }
}

// ---------------------------------------------------------------------------
// recon[b][j] = dec_b[j] + sum_l ids[b][l] * dec_W[l][j]
// ---------------------------------------------------------------------------
__global__ __launch_bounds__(256) void recon_kernel(
    const float* __restrict__ idsF, const float* __restrict__ decW,
    const float* __restrict__ decb, float* __restrict__ recon) {
  int g = blockIdx.x * 256 + threadIdx.x;
  int b = g >> 9, j = g & (CB - 1);
  float s = decb[j];
#pragma unroll
  for (int l = 0; l < NL; ++l)
    s += idsF[(size_t)b * NL + l] * decW[l * CB + j];
  recon[g] = s;
}

extern "C" void kernel_launch(void* const* d_in, const int* in_sizes, int n_in,
                              void* d_out, int out_size, void* d_ws, size_t ws_size,
                              hipStream_t stream) {
  const float* X    = (const float*)d_in[0];
  const float* encW = (const float*)d_in[1];
  const float* encb = (const float*)d_in[2];
  const float* cbs  = (const float*)d_in[3];
  const float* decW = (const float*)d_in[4];
  const float* decb = (const float*)d_in[5];

  float* out = (float*)d_out;
  float* recon = out;
  float* idsF = out + (size_t)BB * CB;

  char* ws = (char*)d_ws;
  float* R = (float*)ws;                       ws += (size_t)BB * CB * sizeof(float);   // 32 MB
  double* cnorm = (double*)ws;                 ws += (size_t)NL * KC * sizeof(double);  // 32 KB
  float* cnormF = (float*)ws;                  ws += (size_t)NL * KC * sizeof(float);   // 16 KB
  float4* cand = (float4*)ws;                  // 16384*4*16B = 1 MB

  cnorm_kernel<<<(NL * KC) / 4, 256, 0, stream>>>(cbs, cnorm, cnormF);
  enc_gemm<<<dim3(CB / 64, BB / 64), 256, 0, stream>>>(X, encW, encb, R);
  for (int l = 0; l < NL; ++l) {
    const float* cbl = cbs + (size_t)l * KC * CB;
    vq_stage1<<<(BB / 64) * 4, 256, 0, stream>>>(cbl, cnormF + (size_t)l * KC, R, cand);
    vq_refine<<<BB / 64, 256, 0, stream>>>(cbl, cnorm + (size_t)l * KC, cand, R, idsF, l);
  }
  recon_kernel<<<(BB * CB) / 256, 256, 0, stream>>>(idsF, decW, decb, recon);
}

// Round 4
// 1385.550 us; speedup vs baseline: 2.2999x; 1.3449x over previous
//
#include <hip/hip_runtime.h>
#include <float.h>
#include <limits.h>

// Problem constants
#define BB 16384   // batch rows
#define DIN 1024   // encoder input dim
#define CB 512     // codebook dim
#define KC 1024    // codewords per layer
#define NL 4       // layers

// Refine margin: must exceed stage1 bf16-split noise (~1e-3). ~10x slack.
#define DELTA 0.01f

typedef __attribute__((ext_vector_type(8))) short short8;
typedef __attribute__((ext_vector_type(4))) float f32x4;

__device__ __forceinline__ unsigned short f2bf(float f) {
  unsigned int u = __float_as_uint(f);
  u = u + 0x7fffu + ((u >> 16) & 1u);
  return (unsigned short)(u >> 16);
}
__device__ __forceinline__ float bf2f(unsigned short h) {
  return __uint_as_float(((unsigned int)h) << 16);
}

// ---------------------------------------------------------------------------
// Split codebooks into bf16 hi/lo. 4 elements per thread.
// ---------------------------------------------------------------------------
__global__ __launch_bounds__(256) void cbsplit_kernel(
    const float* __restrict__ cbs, unsigned short* __restrict__ Chi,
    unsigned short* __restrict__ Clo) {
  int g = (blockIdx.x * 256 + threadIdx.x) * 4;
  float4 v = *(const float4*)(cbs + g);
  float vv[4] = {v.x, v.y, v.z, v.w};
  unsigned short hh[4], ll[4];
#pragma unroll
  for (int i = 0; i < 4; ++i) {
    hh[i] = f2bf(vv[i]);
    ll[i] = f2bf(vv[i] - bf2f(hh[i]));
  }
  *(ushort4*)(Chi + g) = make_ushort4(hh[0], hh[1], hh[2], hh[3]);
  *(ushort4*)(Clo + g) = make_ushort4(ll[0], ll[1], ll[2], ll[3]);
}

// ---------------------------------------------------------------------------
// cnorm[l*KC+k] = ||codebooks[l][k]||^2, fp64 (refine) + fp32 (stage1)
// ---------------------------------------------------------------------------
__global__ __launch_bounds__(256) void cnorm_kernel(
    const float* __restrict__ cbs, double* __restrict__ cnorm,
    float* __restrict__ cnormF) {
  int gw = (blockIdx.x * blockDim.x + threadIdx.x) >> 6;
  int lane = threadIdx.x & 63;
  if (gw >= NL * KC) return;
  const float* row = cbs + (size_t)gw * CB;
  double s = 0.0;
  for (int i = lane; i < CB; i += 64) {
    double v = (double)row[i];
    s += v * v;
  }
#pragma unroll
  for (int off = 32; off > 0; off >>= 1)
    s += __shfl_down(s, off, 64);
  if (lane == 0) { cnorm[gw] = s; cnormF[gw] = (float)s; }
}

// ---------------------------------------------------------------------------
// Encoder GEMM (fp64 accumulation) + bf16 hi/lo split epilogue.
// ---------------------------------------------------------------------------
__global__ __launch_bounds__(256) void enc_gemm(
    const float* __restrict__ X, const float* __restrict__ W,
    const float* __restrict__ bias, float* __restrict__ R,
    unsigned short* __restrict__ Rhi, unsigned short* __restrict__ Rlo) {
  __shared__ float As[16][64];
  __shared__ float Bs[16][64];
  int tid = threadIdx.x;
  int tx = tid & 15, ty = tid >> 4;
  int row0 = blockIdx.y * 64, col0 = blockIdx.x * 64;

  double acc[4][4] = {};
  for (int k0 = 0; k0 < DIN; k0 += 16) {
    {
      int r = tid >> 2, kk = (tid & 3) << 2;
      float4 a = *(const float4*)(X + (size_t)(row0 + r) * DIN + k0 + kk);
      As[kk + 0][r] = a.x; As[kk + 1][r] = a.y;
      As[kk + 2][r] = a.z; As[kk + 3][r] = a.w;
    }
    {
      int kk = tid >> 4, c = (tid & 15) << 2;
      float4 b = *(const float4*)(W + (size_t)(k0 + kk) * CB + col0 + c);
      *(float4*)&Bs[kk][c] = b;
    }
    __syncthreads();
#pragma unroll
    for (int kk = 0; kk < 16; ++kk) {
      float4 av = *(const float4*)&As[kk][ty << 2];
      float4 bv = *(const float4*)&Bs[kk][tx << 2];
      double a[4] = {(double)av.x, (double)av.y, (double)av.z, (double)av.w};
      double b[4] = {(double)bv.x, (double)bv.y, (double)bv.z, (double)bv.w};
#pragma unroll
      for (int i = 0; i < 4; ++i)
#pragma unroll
        for (int j = 0; j < 4; ++j)
          acc[i][j] += a[i] * b[j];
    }
    __syncthreads();
  }
#pragma unroll
  for (int i = 0; i < 4; ++i) {
#pragma unroll
    for (int j = 0; j < 4; ++j) {
      int r = row0 + (ty << 2) + i, c = col0 + (tx << 2) + j;
      float v = (float)(acc[i][j] + (double)bias[c]);
      size_t o = (size_t)r * CB + c;
      R[o] = v;
      unsigned short h = f2bf(v);
      Rhi[o] = h;
      Rlo[o] = f2bf(v - bf2f(h));
    }
  }
}

// ---------------------------------------------------------------------------
// Stage 1: 3-term bf16-split MFMA distance GEMM, 128x128 tile, BK=32.
// S = Rhi*Chi + Rhi*Clo + Rlo*Chi (fp32 acc); d = cnorm - 2S; per-row top-2
// per 128-col block -> cand[row*8 + colblock].
// RACE FIX vs R3: the two wn (col-half) waves merge via sRed in LDS before
// a single thread per row writes cand.
// ---------------------------------------------------------------------------
__global__ __launch_bounds__(256) void vq_stage1(
    const unsigned short* __restrict__ Rhi, const unsigned short* __restrict__ Rlo,
    const unsigned short* __restrict__ Chi, const unsigned short* __restrict__ Clo,
    const float* __restrict__ cnormF, float4* __restrict__ cand) {
  // LDS: 4 tiles (Ahi,Alo,Bhi,Blo), each [4 k-chunk planes][128 rows] x 16B
  __shared__ __align__(16) char lds[32768];
  __shared__ float4 sRed[128][2];  // per-row top-2 of each col-half
  int tid = threadIdx.x;
  int wave = tid >> 6, lane = tid & 63;
  int wm = wave >> 1, wn = wave & 1;
  int q = lane >> 4, l15 = lane & 15;
  int rb = blockIdx.x >> 3, cbk = blockIdx.x & 7;
  int row0 = rb * 128, n0 = cbk * 128;

  f32x4 acc[4][4];
#pragma unroll
  for (int i = 0; i < 4; ++i)
#pragma unroll
    for (int j = 0; j < 4; ++j)
      acc[i][j] = (f32x4){0.f, 0.f, 0.f, 0.f};

  const unsigned short* srcs[4] = {Rhi, Rlo, Chi, Clo};

  for (int kt = 0; kt < 16; ++kt) {
    int k0 = kt * 32;
    __syncthreads();
    // staging: 32 issues of 1KB (64 rows x 16B), wave w handles srcs[w]
#pragma unroll
    for (int s = 0; s < 8; ++s) {
      int I = wave * 8 + s;
      int src_i = I >> 3;           // == wave: 0..3 -> Rhi,Rlo,Chi,Clo
      int qq = (I >> 1) & 3, h = I & 1;
      int rowg = (src_i >= 2 ? n0 : row0) + h * 64 + lane;
      const unsigned short* gp = srcs[src_i] + (size_t)rowg * CB + k0 + qq * 8;
      char* lp = lds + src_i * 8192 + (qq * 128 + h * 64) * 16;
      __builtin_amdgcn_global_load_lds(
          (const __attribute__((address_space(1))) void*)gp,
          (__attribute__((address_space(3))) void*)lp, 16, 0, 0);
    }
    __syncthreads();

    short8 ahi[4], alo[4];
#pragma unroll
    for (int ti = 0; ti < 4; ++ti) {
      int r = q * 128 + wm * 64 + ti * 16 + l15;
      ahi[ti] = *(const short8*)(lds + r * 16);
      alo[ti] = *(const short8*)(lds + 8192 + r * 16);
    }
#pragma unroll
    for (int tj = 0; tj < 4; ++tj) {
      int rn = q * 128 + wn * 64 + tj * 16 + l15;
      short8 bhi = *(const short8*)(lds + 16384 + rn * 16);
      short8 blo = *(const short8*)(lds + 24576 + rn * 16);
#pragma unroll
      for (int ti = 0; ti < 4; ++ti) {
        acc[ti][tj] = __builtin_amdgcn_mfma_f32_16x16x32_bf16(ahi[ti], bhi, acc[ti][tj], 0, 0, 0);
        acc[ti][tj] = __builtin_amdgcn_mfma_f32_16x16x32_bf16(ahi[ti], blo, acc[ti][tj], 0, 0, 0);
        acc[ti][tj] = __builtin_amdgcn_mfma_f32_16x16x32_bf16(alo[ti], bhi, acc[ti][tj], 0, 0, 0);
      }
    }
  }

  // Epilogue: d = cn - 2S; per-row top-2 over this wave's 64 cols, then
  // cross-wn merge via sRed.
  float cn[4]; int coln[4];
#pragma unroll
  for (int tj = 0; tj < 4; ++tj) {
    coln[tj] = n0 + wn * 64 + tj * 16 + l15;
    cn[tj] = cnormF[coln[tj]];
  }
#pragma unroll
  for (int ti = 0; ti < 4; ++ti) {
#pragma unroll
    for (int r = 0; r < 4; ++r) {
      float m1 = FLT_MAX, m2 = FLT_MAX;
      int i1 = INT_MAX, i2 = INT_MAX;
#pragma unroll
      for (int tj = 0; tj < 4; ++tj) {
        float v = cn[tj] - 2.0f * acc[ti][tj][r];
        int ix = coln[tj];
        if (v < m1 || (v == m1 && ix < i1)) {
          m2 = m1; i2 = i1; m1 = v; i1 = ix;
        } else if (v < m2 || (v == m2 && ix < i2)) {
          m2 = v; i2 = ix;
        }
      }
      // butterfly across the 16-lane group (lanes hold different cols of the
      // same D row: row = q*4+r, col = l15-dependent)
#pragma unroll
      for (int mask = 1; mask <= 8; mask <<= 1) {
        float om1 = __shfl_xor(m1, mask, 64);
        int   oi1 = __shfl_xor(i1, mask, 64);
        float om2 = __shfl_xor(m2, mask, 64);
        int   oi2 = __shfl_xor(i2, mask, 64);
        if (om1 < m1 || (om1 == m1 && oi1 < i1)) {
          m2 = m1; i2 = i1; m1 = om1; i1 = oi1;
        } else if (om1 < m2 || (om1 == m2 && oi1 < i2)) {
          m2 = om1; i2 = oi1;
        }
        if (om2 < m1 || (om2 == m1 && oi2 < i1)) {
          m2 = m1; i2 = i1; m1 = om2; i1 = oi2;
        } else if (om2 < m2 || (om2 == m2 && oi2 < i2)) {
          m2 = om2; i2 = oi2;
        }
      }
      if (l15 == 0) {
        int rit = wm * 64 + ti * 16 + q * 4 + r;
        sRed[rit][wn] =
            make_float4(m1, __int_as_float(i1), m2, __int_as_float(i2));
      }
    }
  }
  __syncthreads();

  if (tid < 128) {
    float4 e0 = sRed[tid][0], e1 = sRed[tid][1];
    float v[4] = {e0.x, e0.z, e1.x, e1.z};
    int ix[4] = {__float_as_int(e0.y), __float_as_int(e0.w),
                 __float_as_int(e1.y), __float_as_int(e1.w)};
    float M1 = FLT_MAX, M2 = FLT_MAX;
    int I1 = INT_MAX, I2 = INT_MAX;
#pragma unroll
    for (int p = 0; p < 4; ++p) {
      if (v[p] < M1 || (v[p] == M1 && ix[p] < I1)) {
        M2 = M1; I2 = I1; M1 = v[p]; I1 = ix[p];
      } else if (v[p] < M2 || (v[p] == M2 && ix[p] < I2)) {
        M2 = v[p]; I2 = ix[p];
      }
    }
    cand[(size_t)(row0 + tid) * 8 + cbk] =
        make_float4(M1, __int_as_float(I1), M2, __int_as_float(I2));
  }
}

// ---------------------------------------------------------------------------
// Stage 2: combine 8 chunk top-2s; fp64-refine near-ties (vs fp32 R);
// write id; update residual + bf16 hi/lo split in place.
// ---------------------------------------------------------------------------
__global__ __launch_bounds__(256) void vq_refine(
    const float* __restrict__ cb, const double* __restrict__ cnorm,
    const float4* __restrict__ cand, float* __restrict__ R,
    unsigned short* __restrict__ Rhi, unsigned short* __restrict__ Rlo,
    float* __restrict__ idsF, int layer) {
  __shared__ int sIdx[64][16];
  __shared__ int sCnt[64];
  __shared__ int sBest[64];

  int tid = threadIdx.x;
  int row0 = blockIdx.x * 64;

  if (tid < 64) {
    int row = row0 + tid;
    float v[16]; int ix[16];
#pragma unroll
    for (int c = 0; c < 8; ++c) {
      float4 e = cand[(size_t)row * 8 + c];
      v[2 * c] = e.x;     ix[2 * c] = __float_as_int(e.y);
      v[2 * c + 1] = e.z; ix[2 * c + 1] = __float_as_int(e.w);
    }
    float M = FLT_MAX; int I = INT_MAX;
#pragma unroll
    for (int p = 0; p < 16; ++p)
      if (v[p] < M || (v[p] == M && ix[p] < I)) { M = v[p]; I = ix[p]; }
    int cnt = 0;
#pragma unroll
    for (int p = 0; p < 16; ++p)
      if (v[p] < M + DELTA && cnt < 16) sIdx[tid][cnt++] = ix[p];
    sCnt[tid] = cnt;
    sBest[tid] = I;
  }
  __syncthreads();

  int wave = tid >> 6, lane = tid & 63;
  for (int r = wave * 16; r < wave * 16 + 16; ++r) {
    int cnt = sCnt[r];
    if (cnt < 2) continue;
    double bestD = 1e300; int bestI = INT_MAX;
    const float* rrow = R + (size_t)(row0 + r) * CB;
    for (int c = 0; c < cnt; ++c) {
      int idx = sIdx[r][c];
      const float* crow = cb + (size_t)idx * CB;
      double s = 0.0;
      for (int e = lane; e < CB; e += 64)
        s += (double)rrow[e] * (double)crow[e];
#pragma unroll
      for (int off = 32; off > 0; off >>= 1)
        s += __shfl_xor(s, off, 64);
      double d = cnorm[idx] - 2.0 * s;
      if (d < bestD || (d == bestD && idx < bestI)) { bestD = d; bestI = idx; }
    }
    if (lane == 0) sBest[r] = bestI;
  }
  __syncthreads();

  if (tid < 64)
    idsF[(size_t)(row0 + tid) * NL + layer] = (float)sBest[tid];

  for (int e = tid; e < 64 * CB; e += 256) {
    int r = e >> 9, d = e & (CB - 1);
    size_t o = (size_t)(row0 + r) * CB + d;
    float nv = R[o] - cb[(size_t)sBest[r] * CB + d];
    R[o] = nv;
    unsigned short h = f2bf(nv);
    Rhi[o] = h;
    Rlo[o] = f2bf(nv - bf2f(h));
  }
}

// ---------------------------------------------------------------------------
// recon[b][j] = dec_b[j] + sum_l ids[b][l] * dec_W[l][j]
// ---------------------------------------------------------------------------
__global__ __launch_bounds__(256) void recon_kernel(
    const float* __restrict__ idsF, const float* __restrict__ decW,
    const float* __restrict__ decb, float* __restrict__ recon) {
  int g = blockIdx.x * 256 + threadIdx.x;
  int b = g >> 9, j = g & (CB - 1);
  float s = decb[j];
#pragma unroll
  for (int l = 0; l < NL; ++l)
    s += idsF[(size_t)b * NL + l] * decW[l * CB + j];
  recon[g] = s;
}

extern "C" void kernel_launch(void* const* d_in, const int* in_sizes, int n_in,
                              void* d_out, int out_size, void* d_ws, size_t ws_size,
                              hipStream_t stream) {
  const float* X    = (const float*)d_in[0];
  const float* encW = (const float*)d_in[1];
  const float* encb = (const float*)d_in[2];
  const float* cbs  = (const float*)d_in[3];
  const float* decW = (const float*)d_in[4];
  const float* decb = (const float*)d_in[5];

  float* out = (float*)d_out;
  float* recon = out;
  float* idsF = out + (size_t)BB * CB;

  char* ws = (char*)d_ws;
  float* R = (float*)ws;                 ws += (size_t)BB * CB * 4;        // 32 MB
  unsigned short* Rhi = (unsigned short*)ws; ws += (size_t)BB * CB * 2;    // 16 MB
  unsigned short* Rlo = (unsigned short*)ws; ws += (size_t)BB * CB * 2;    // 16 MB
  unsigned short* Chi = (unsigned short*)ws; ws += (size_t)NL * KC * CB * 2; // 4 MB
  unsigned short* Clo = (unsigned short*)ws; ws += (size_t)NL * KC * CB * 2; // 4 MB
  double* cnorm = (double*)ws;           ws += (size_t)NL * KC * 8;        // 32 KB
  float* cnormF = (float*)ws;            ws += (size_t)NL * KC * 4;        // 16 KB
  float4* cand = (float4*)ws;            // [BB][8] float4 = 2 MB

  cbsplit_kernel<<<(NL * KC * CB) / 1024, 256, 0, stream>>>(cbs, Chi, Clo);
  cnorm_kernel<<<(NL * KC) / 4, 256, 0, stream>>>(cbs, cnorm, cnormF);
  enc_gemm<<<dim3(CB / 64, BB / 64), 256, 0, stream>>>(X, encW, encb, R, Rhi, Rlo);
  for (int l = 0; l < NL; ++l) {
    const float* cbl = cbs + (size_t)l * KC * CB;
    vq_stage1<<<(BB / 128) * 8, 256, 0, stream>>>(
        Rhi, Rlo, Chi + (size_t)l * KC * CB, Clo + (size_t)l * KC * CB,
        cnormF + (size_t)l * KC, cand);
    vq_refine<<<BB / 64, 256, 0, stream>>>(cbl, cnorm + (size_t)l * KC, cand,
                                           R, Rhi, Rlo, idsF, l);
  }
  recon_kernel<<<(BB * CB) / 256, 256, 0, stream>>>(idsF, decW, decb, recon);
}

// Round 5
// 1332.798 us; speedup vs baseline: 2.3909x; 1.0396x over previous
//
#include <hip/hip_runtime.h>
#include <float.h>
#include <limits.h>

// Problem constants
#define BB 16384   // batch rows
#define DIN 1024   // encoder input dim
#define CB 512     // codebook dim
#define KC 1024    // codewords per layer
#define NL 4       // layers

// Refine margin: must exceed stage1 bf16-split noise (~1e-3). ~10x slack.
#define DELTA 0.01f

typedef __attribute__((ext_vector_type(8))) short short8;
typedef __attribute__((ext_vector_type(4))) float f32x4;

__device__ __forceinline__ unsigned short f2bf(float f) {
  unsigned int u = __float_as_uint(f);
  u = u + 0x7fffu + ((u >> 16) & 1u);
  return (unsigned short)(u >> 16);
}
__device__ __forceinline__ float bf2f(unsigned short h) {
  return __uint_as_float(((unsigned int)h) << 16);
}

// ---------------------------------------------------------------------------
// Split codebooks into bf16 hi/lo. 4 elements per thread.
// ---------------------------------------------------------------------------
__global__ __launch_bounds__(256) void cbsplit_kernel(
    const float* __restrict__ cbs, unsigned short* __restrict__ Chi,
    unsigned short* __restrict__ Clo) {
  int g = (blockIdx.x * 256 + threadIdx.x) * 4;
  float4 v = *(const float4*)(cbs + g);
  float vv[4] = {v.x, v.y, v.z, v.w};
  unsigned short hh[4], ll[4];
#pragma unroll
  for (int i = 0; i < 4; ++i) {
    hh[i] = f2bf(vv[i]);
    ll[i] = f2bf(vv[i] - bf2f(hh[i]));
  }
  *(ushort4*)(Chi + g) = make_ushort4(hh[0], hh[1], hh[2], hh[3]);
  *(ushort4*)(Clo + g) = make_ushort4(ll[0], ll[1], ll[2], ll[3]);
}

// ---------------------------------------------------------------------------
// cnorm[l*KC+k] = ||codebooks[l][k]||^2, fp64 (refine) + fp32 (stage1)
// ---------------------------------------------------------------------------
__global__ __launch_bounds__(256) void cnorm_kernel(
    const float* __restrict__ cbs, double* __restrict__ cnorm,
    float* __restrict__ cnormF) {
  int gw = (blockIdx.x * blockDim.x + threadIdx.x) >> 6;
  int lane = threadIdx.x & 63;
  if (gw >= NL * KC) return;
  const float* row = cbs + (size_t)gw * CB;
  double s = 0.0;
  for (int i = lane; i < CB; i += 64) {
    double v = (double)row[i];
    s += v * v;
  }
#pragma unroll
  for (int off = 32; off > 0; off >>= 1)
    s += __shfl_down(s, off, 64);
  if (lane == 0) { cnorm[gw] = s; cnormF[gw] = (float)s; }
}

// ---------------------------------------------------------------------------
// Encoder GEMM: R = X @ W + b, fp64 accumulation.
// 128x128 tile, 8x8 per thread: 64 fp64 FMA per 4 ds_read_b128 -> VALU-bound
// (R4's 4x4 was LDS-port-bound: 16 FMA per 2 reads, 384 vs 256 cy/CU).
// XCD swizzle: 4 col-blocks of one row-block share an XCD (X fetched once).
// Per-element accumulation order (k ascending) identical to R4 -> bitwise
// same R -> same argmin decisions downstream.
// ---------------------------------------------------------------------------
__global__ __launch_bounds__(256, 2) void enc_gemm(
    const float* __restrict__ X, const float* __restrict__ W,
    const float* __restrict__ bias, float* __restrict__ R,
    unsigned short* __restrict__ Rhi, unsigned short* __restrict__ Rlo) {
  __shared__ float As[16][128];   // [kk][m]
  __shared__ float Bs[16][132];   // [c_grp][kk*8+j], pad to 132 (2-way max)
  int tid = threadIdx.x;
  int tx = tid & 15, ty = tid >> 4;
  int g = blockIdx.x;
  int rb = (g & 7) + ((g >> 5) << 3);  // 4 col-blocks of rb share g&7 (XCD)
  int cb4 = (g >> 3) & 3;
  int row0 = rb * 128, col0 = cb4 * 128;

  int sr = tid >> 1, skb = (tid & 1) * 8;  // A staging: row, k-base
  int bc = tid & 15, bk = tid >> 4;        // B staging: c-group, kk

  double acc[8][8] = {};
  for (int k0 = 0; k0 < DIN; k0 += 16) {
    float4 a0 = *(const float4*)(X + (size_t)(row0 + sr) * DIN + k0 + skb);
    float4 a1 = *(const float4*)(X + (size_t)(row0 + sr) * DIN + k0 + skb + 4);
    float4 b0 = *(const float4*)(W + (size_t)(k0 + bk) * CB + col0 + bc * 8);
    float4 b1 = *(const float4*)(W + (size_t)(k0 + bk) * CB + col0 + bc * 8 + 4);
    __syncthreads();  // previous iteration's LDS reads done
    As[skb + 0][sr] = a0.x; As[skb + 1][sr] = a0.y;
    As[skb + 2][sr] = a0.z; As[skb + 3][sr] = a0.w;
    As[skb + 4][sr] = a1.x; As[skb + 5][sr] = a1.y;
    As[skb + 6][sr] = a1.z; As[skb + 7][sr] = a1.w;
    *(float4*)&Bs[bc][bk * 8] = b0;
    *(float4*)&Bs[bc][bk * 8 + 4] = b1;
    __syncthreads();
#pragma unroll
    for (int kk = 0; kk < 16; ++kk) {
      float4 av0 = *(const float4*)&As[kk][ty * 8];
      float4 av1 = *(const float4*)&As[kk][ty * 8 + 4];
      float4 bv0 = *(const float4*)&Bs[tx][kk * 8];
      float4 bv1 = *(const float4*)&Bs[tx][kk * 8 + 4];
      double a[8] = {(double)av0.x, (double)av0.y, (double)av0.z, (double)av0.w,
                     (double)av1.x, (double)av1.y, (double)av1.z, (double)av1.w};
      double b[8] = {(double)bv0.x, (double)bv0.y, (double)bv0.z, (double)bv0.w,
                     (double)bv1.x, (double)bv1.y, (double)bv1.z, (double)bv1.w};
#pragma unroll
      for (int i = 0; i < 8; ++i)
#pragma unroll
        for (int j = 0; j < 8; ++j)
          acc[i][j] += a[i] * b[j];
    }
  }

  double bb[8];
#pragma unroll
  for (int j = 0; j < 8; ++j) bb[j] = (double)bias[col0 + tx * 8 + j];
#pragma unroll
  for (int i = 0; i < 8; ++i) {
    int r = row0 + ty * 8 + i;
    size_t o = (size_t)r * CB + col0 + tx * 8;
    float vr[8];
    unsigned short vh[8], vl[8];
#pragma unroll
    for (int j = 0; j < 8; ++j) {
      float v = (float)(acc[i][j] + bb[j]);
      vr[j] = v;
      vh[j] = f2bf(v);
      vl[j] = f2bf(v - bf2f(vh[j]));
    }
    *(float4*)(R + o) = make_float4(vr[0], vr[1], vr[2], vr[3]);
    *(float4*)(R + o + 4) = make_float4(vr[4], vr[5], vr[6], vr[7]);
    *(ushort4*)(Rhi + o) = make_ushort4(vh[0], vh[1], vh[2], vh[3]);
    *(ushort4*)(Rhi + o + 4) = make_ushort4(vh[4], vh[5], vh[6], vh[7]);
    *(ushort4*)(Rlo + o) = make_ushort4(vl[0], vl[1], vl[2], vl[3]);
    *(ushort4*)(Rlo + o + 4) = make_ushort4(vl[4], vl[5], vl[6], vl[7]);
  }
}

// ---------------------------------------------------------------------------
// Stage 1: 3-term bf16-split MFMA distance GEMM, 128x128 tile, BK=32.
// vs R4: (a) staging uses explicit wave-uniform branch (no dynamically
// indexed pointer array -> no cndmask/scratch chains), hoisted row bases;
// (b) all 8 B-frags loaded once per kt, MFMAs issued term-major (dependency
// chain distance 3 -> 16); (c) XCD swizzle: the 8 col-blocks of one
// row-block share an XCD (Rhi/Rlo fetched once per XCD, not 8x).
// ---------------------------------------------------------------------------
__global__ __launch_bounds__(256) void vq_stage1(
    const unsigned short* __restrict__ Rhi, const unsigned short* __restrict__ Rlo,
    const unsigned short* __restrict__ Chi, const unsigned short* __restrict__ Clo,
    const float* __restrict__ cnormF, float4* __restrict__ cand) {
  // LDS: 4 tiles (Ahi,Alo,Bhi,Blo), each [4 k-chunk planes][128 rows] x 16B
  __shared__ __align__(16) char lds[32768];
  __shared__ float4 sRed[128][2];  // per-row top-2 of each col-half
  int tid = threadIdx.x;
  int wave = tid >> 6, lane = tid & 63;
  int wm = wave >> 1, wn = wave & 1;
  int q = lane >> 4, l15 = lane & 15;
  int g = blockIdx.x;
  int rb = (g & 7) + ((g >> 6) << 3);  // 8 col-blocks of rb share g&7 (XCD)
  int cbk = (g >> 3) & 7;
  int row0 = rb * 128, n0 = cbk * 128;

  f32x4 acc[4][4];
#pragma unroll
  for (int i = 0; i < 4; ++i)
#pragma unroll
    for (int j = 0; j < 4; ++j)
      acc[i][j] = (f32x4){0.f, 0.f, 0.f, 0.f};

  // wave-uniform staging source (wave 0:Rhi 1:Rlo 2:Chi 3:Clo)
  const unsigned short* gsrc;
  int rbase;
  if (wave == 0)      { gsrc = Rhi; rbase = row0; }
  else if (wave == 1) { gsrc = Rlo; rbase = row0; }
  else if (wave == 2) { gsrc = Chi; rbase = n0; }
  else                { gsrc = Clo; rbase = n0; }
  const unsigned short* g0 = gsrc + (size_t)(rbase + lane) * CB;
  const unsigned short* g1 = g0 + (size_t)64 * CB;
  char* lbase = lds + wave * 8192;

  for (int kt = 0; kt < 16; ++kt) {
    int k0 = kt * 32;
    __syncthreads();
#pragma unroll
    for (int qq = 0; qq < 4; ++qq) {
      __builtin_amdgcn_global_load_lds(
          (const __attribute__((address_space(1))) void*)(g0 + k0 + qq * 8),
          (__attribute__((address_space(3))) void*)(lbase + (qq * 128) * 16),
          16, 0, 0);
      __builtin_amdgcn_global_load_lds(
          (const __attribute__((address_space(1))) void*)(g1 + k0 + qq * 8),
          (__attribute__((address_space(3))) void*)(lbase + (qq * 128 + 64) * 16),
          16, 0, 0);
    }
    __syncthreads();

    short8 ahi[4], alo[4], bhi[4], blo[4];
#pragma unroll
    for (int ti = 0; ti < 4; ++ti) {
      int r = q * 128 + wm * 64 + ti * 16 + l15;
      ahi[ti] = *(const short8*)(lds + r * 16);
      alo[ti] = *(const short8*)(lds + 8192 + r * 16);
    }
#pragma unroll
    for (int tj = 0; tj < 4; ++tj) {
      int rn = q * 128 + wn * 64 + tj * 16 + l15;
      bhi[tj] = *(const short8*)(lds + 16384 + rn * 16);
      blo[tj] = *(const short8*)(lds + 24576 + rn * 16);
    }
    // term-major: per acc element the per-kt order stays hh,hl,lh (bitwise
    // identical to R4), but consecutive MFMAs hit different accumulators.
#pragma unroll
    for (int tj = 0; tj < 4; ++tj)
#pragma unroll
      for (int ti = 0; ti < 4; ++ti)
        acc[ti][tj] = __builtin_amdgcn_mfma_f32_16x16x32_bf16(ahi[ti], bhi[tj], acc[ti][tj], 0, 0, 0);
#pragma unroll
    for (int tj = 0; tj < 4; ++tj)
#pragma unroll
      for (int ti = 0; ti < 4; ++ti)
        acc[ti][tj] = __builtin_amdgcn_mfma_f32_16x16x32_bf16(ahi[ti], blo[tj], acc[ti][tj], 0, 0, 0);
#pragma unroll
    for (int tj = 0; tj < 4; ++tj)
#pragma unroll
      for (int ti = 0; ti < 4; ++ti)
        acc[ti][tj] = __builtin_amdgcn_mfma_f32_16x16x32_bf16(alo[ti], bhi[tj], acc[ti][tj], 0, 0, 0);
  }

  // Epilogue: d = cn - 2S; per-row top-2 over this wave's 64 cols, then
  // cross-wn merge via sRed.
  float cn[4]; int coln[4];
#pragma unroll
  for (int tj = 0; tj < 4; ++tj) {
    coln[tj] = n0 + wn * 64 + tj * 16 + l15;
    cn[tj] = cnormF[coln[tj]];
  }
#pragma unroll
  for (int ti = 0; ti < 4; ++ti) {
#pragma unroll
    for (int r = 0; r < 4; ++r) {
      float m1 = FLT_MAX, m2 = FLT_MAX;
      int i1 = INT_MAX, i2 = INT_MAX;
#pragma unroll
      for (int tj = 0; tj < 4; ++tj) {
        float v = cn[tj] - 2.0f * acc[ti][tj][r];
        int ix = coln[tj];
        if (v < m1 || (v == m1 && ix < i1)) {
          m2 = m1; i2 = i1; m1 = v; i1 = ix;
        } else if (v < m2 || (v == m2 && ix < i2)) {
          m2 = v; i2 = ix;
        }
      }
#pragma unroll
      for (int mask = 1; mask <= 8; mask <<= 1) {
        float om1 = __shfl_xor(m1, mask, 64);
        int   oi1 = __shfl_xor(i1, mask, 64);
        float om2 = __shfl_xor(m2, mask, 64);
        int   oi2 = __shfl_xor(i2, mask, 64);
        if (om1 < m1 || (om1 == m1 && oi1 < i1)) {
          m2 = m1; i2 = i1; m1 = om1; i1 = oi1;
        } else if (om1 < m2 || (om1 == m2 && oi1 < i2)) {
          m2 = om1; i2 = oi1;
        }
        if (om2 < m1 || (om2 == m1 && oi2 < i1)) {
          m2 = m1; i2 = i1; m1 = om2; i1 = oi2;
        } else if (om2 < m2 || (om2 == m2 && oi2 < i2)) {
          m2 = om2; i2 = oi2;
        }
      }
      if (l15 == 0) {
        int rit = wm * 64 + ti * 16 + q * 4 + r;
        sRed[rit][wn] =
            make_float4(m1, __int_as_float(i1), m2, __int_as_float(i2));
      }
    }
  }
  __syncthreads();

  if (tid < 128) {
    float4 e0 = sRed[tid][0], e1 = sRed[tid][1];
    float v[4] = {e0.x, e0.z, e1.x, e1.z};
    int ix[4] = {__float_as_int(e0.y), __float_as_int(e0.w),
                 __float_as_int(e1.y), __float_as_int(e1.w)};
    float M1 = FLT_MAX, M2 = FLT_MAX;
    int I1 = INT_MAX, I2 = INT_MAX;
#pragma unroll
    for (int p = 0; p < 4; ++p) {
      if (v[p] < M1 || (v[p] == M1 && ix[p] < I1)) {
        M2 = M1; I2 = I1; M1 = v[p]; I1 = ix[p];
      } else if (v[p] < M2 || (v[p] == M2 && ix[p] < I2)) {
        M2 = v[p]; I2 = ix[p];
      }
    }
    cand[(size_t)(row0 + tid) * 8 + cbk] =
        make_float4(M1, __int_as_float(I1), M2, __int_as_float(I2));
  }
}

// ---------------------------------------------------------------------------
// Stage 2: combine 8 chunk top-2s; fp64-refine near-ties (vs fp32 R);
// write id; update residual + bf16 hi/lo split in place.
// ---------------------------------------------------------------------------
__global__ __launch_bounds__(256) void vq_refine(
    const float* __restrict__ cb, const double* __restrict__ cnorm,
    const float4* __restrict__ cand, float* __restrict__ R,
    unsigned short* __restrict__ Rhi, unsigned short* __restrict__ Rlo,
    float* __restrict__ idsF, int layer) {
  __shared__ int sIdx[64][16];
  __shared__ int sCnt[64];
  __shared__ int sBest[64];

  int tid = threadIdx.x;
  int row0 = blockIdx.x * 64;

  if (tid < 64) {
    int row = row0 + tid;
    float v[16]; int ix[16];
#pragma unroll
    for (int c = 0; c < 8; ++c) {
      float4 e = cand[(size_t)row * 8 + c];
      v[2 * c] = e.x;     ix[2 * c] = __float_as_int(e.y);
      v[2 * c + 1] = e.z; ix[2 * c + 1] = __float_as_int(e.w);
    }
    float M = FLT_MAX; int I = INT_MAX;
#pragma unroll
    for (int p = 0; p < 16; ++p)
      if (v[p] < M || (v[p] == M && ix[p] < I)) { M = v[p]; I = ix[p]; }
    int cnt = 0;
#pragma unroll
    for (int p = 0; p < 16; ++p)
      if (v[p] < M + DELTA && cnt < 16) sIdx[tid][cnt++] = ix[p];
    sCnt[tid] = cnt;
    sBest[tid] = I;
  }
  __syncthreads();

  int wave = tid >> 6, lane = tid & 63;
  for (int r = wave * 16; r < wave * 16 + 16; ++r) {
    int cnt = sCnt[r];
    if (cnt < 2) continue;
    double bestD = 1e300; int bestI = INT_MAX;
    const float* rrow = R + (size_t)(row0 + r) * CB;
    for (int c = 0; c < cnt; ++c) {
      int idx = sIdx[r][c];
      const float* crow = cb + (size_t)idx * CB;
      double s = 0.0;
      for (int e = lane; e < CB; e += 64)
        s += (double)rrow[e] * (double)crow[e];
#pragma unroll
      for (int off = 32; off > 0; off >>= 1)
        s += __shfl_xor(s, off, 64);
      double d = cnorm[idx] - 2.0 * s;
      if (d < bestD || (d == bestD && idx < bestI)) { bestD = d; bestI = idx; }
    }
    if (lane == 0) sBest[r] = bestI;
  }
  __syncthreads();

  if (tid < 64)
    idsF[(size_t)(row0 + tid) * NL + layer] = (float)sBest[tid];

  for (int e = tid; e < 64 * CB; e += 256) {
    int r = e >> 9, d = e & (CB - 1);
    size_t o = (size_t)(row0 + r) * CB + d;
    float nv = R[o] - cb[(size_t)sBest[r] * CB + d];
    R[o] = nv;
    unsigned short h = f2bf(nv);
    Rhi[o] = h;
    Rlo[o] = f2bf(nv - bf2f(h));
  }
}

// ---------------------------------------------------------------------------
// recon[b][j] = dec_b[j] + sum_l ids[b][l] * dec_W[l][j]
// ---------------------------------------------------------------------------
__global__ __launch_bounds__(256) void recon_kernel(
    const float* __restrict__ idsF, const float* __restrict__ decW,
    const float* __restrict__ decb, float* __restrict__ recon) {
  int g = blockIdx.x * 256 + threadIdx.x;
  int b = g >> 9, j = g & (CB - 1);
  float s = decb[j];
#pragma unroll
  for (int l = 0; l < NL; ++l)
    s += idsF[(size_t)b * NL + l] * decW[l * CB + j];
  recon[g] = s;
}

extern "C" void kernel_launch(void* const* d_in, const int* in_sizes, int n_in,
                              void* d_out, int out_size, void* d_ws, size_t ws_size,
                              hipStream_t stream) {
  const float* X    = (const float*)d_in[0];
  const float* encW = (const float*)d_in[1];
  const float* encb = (const float*)d_in[2];
  const float* cbs  = (const float*)d_in[3];
  const float* decW = (const float*)d_in[4];
  const float* decb = (const float*)d_in[5];

  float* out = (float*)d_out;
  float* recon = out;
  float* idsF = out + (size_t)BB * CB;

  char* ws = (char*)d_ws;
  float* R = (float*)ws;                 ws += (size_t)BB * CB * 4;        // 32 MB
  unsigned short* Rhi = (unsigned short*)ws; ws += (size_t)BB * CB * 2;    // 16 MB
  unsigned short* Rlo = (unsigned short*)ws; ws += (size_t)BB * CB * 2;    // 16 MB
  unsigned short* Chi = (unsigned short*)ws; ws += (size_t)NL * KC * CB * 2; // 4 MB
  unsigned short* Clo = (unsigned short*)ws; ws += (size_t)NL * KC * CB * 2; // 4 MB
  double* cnorm = (double*)ws;           ws += (size_t)NL * KC * 8;        // 32 KB
  float* cnormF = (float*)ws;            ws += (size_t)NL * KC * 4;        // 16 KB
  float4* cand = (float4*)ws;            // [BB][8] float4 = 2 MB

  cbsplit_kernel<<<(NL * KC * CB) / 1024, 256, 0, stream>>>(cbs, Chi, Clo);
  cnorm_kernel<<<(NL * KC) / 4, 256, 0, stream>>>(cbs, cnorm, cnormF);
  enc_gemm<<<(BB / 128) * (CB / 128), 256, 0, stream>>>(X, encW, encb, R, Rhi, Rlo);
  for (int l = 0; l < NL; ++l) {
    const float* cbl = cbs + (size_t)l * KC * CB;
    vq_stage1<<<(BB / 128) * 8, 256, 0, stream>>>(
        Rhi, Rlo, Chi + (size_t)l * KC * CB, Clo + (size_t)l * KC * CB,
        cnormF + (size_t)l * KC, cand);
    vq_refine<<<BB / 64, 256, 0, stream>>>(cbl, cnorm + (size_t)l * KC, cand,
                                           R, Rhi, Rlo, idsF, l);
  }
  recon_kernel<<<(BB * CB) / 256, 256, 0, stream>>>(idsF, decW, decb, recon);
}

// Round 6
// 930.636 us; speedup vs baseline: 3.4241x; 1.4321x over previous
//
#include <hip/hip_runtime.h>
#include <float.h>
#include <limits.h>

// Problem constants
#define BB 16384   // batch rows
#define DIN 1024   // encoder input dim
#define CB 512     // codebook dim
#define KC 1024    // codewords per layer
#define NL 4       // layers

// Refine margin: must exceed stage1 bf16-split noise (~1e-3). ~10x slack.
#define DELTA 0.01f

typedef __attribute__((ext_vector_type(8))) short short8;
typedef __attribute__((ext_vector_type(4))) float f32x4;

__device__ __forceinline__ unsigned short f2bf(float f) {
  unsigned int u = __float_as_uint(f);
  u = u + 0x7fffu + ((u >> 16) & 1u);
  return (unsigned short)(u >> 16);
}
__device__ __forceinline__ float bf2f(unsigned short h) {
  return __uint_as_float(((unsigned int)h) << 16);
}

// Staged layout (shorts) for matrix M[rows][512]:
//   off(row,k) = ((row>>4)*16 + (k>>5))*512 + (((k>>3)&3)*16 + (row&15))*8 + (k&7)
// = the MFMA A/B fragment lane image: per (16-row group, kt) a 1KB plane where
// lane (q*16+r16) holds k = kt*32 + q*8 + j. Staging = contiguous 1KB loads;
// fragment ds_read_b128 = base + plane + lane*16 (conflict-free).
__device__ __forceinline__ size_t staged_off(int row, int k) {
  return ((size_t)(row >> 4) * 16 + (k >> 5)) * 512 +
         (((k >> 3) & 3) * 16 + (row & 15)) * 8 + (k & 7);
}

// ---------------------------------------------------------------------------
// Split codebooks into bf16 hi/lo, written in staged layout.
// ---------------------------------------------------------------------------
__global__ __launch_bounds__(256) void cbsplit_kernel(
    const float* __restrict__ cbs, unsigned short* __restrict__ Chi,
    unsigned short* __restrict__ Clo) {
  int g = (blockIdx.x * 256 + threadIdx.x) * 4;  // flat over NL*KC*CB, k-aligned-4
  int k = g & (CB - 1);
  int lr = g >> 9;
  int layer = lr >> 10, row = lr & (KC - 1);
  float4 v = *(const float4*)(cbs + g);
  float vv[4] = {v.x, v.y, v.z, v.w};
  unsigned short hh[4], ll[4];
#pragma unroll
  for (int i = 0; i < 4; ++i) {
    hh[i] = f2bf(vv[i]);
    ll[i] = f2bf(vv[i] - bf2f(hh[i]));
  }
  size_t off = (size_t)layer * (KC / 16) * 8192 + staged_off(row, k);
  *(ushort4*)(Chi + off) = make_ushort4(hh[0], hh[1], hh[2], hh[3]);
  *(ushort4*)(Clo + off) = make_ushort4(ll[0], ll[1], ll[2], ll[3]);
}

// ---------------------------------------------------------------------------
// cnorm[l*KC+k] = ||codebooks[l][k]||^2, fp64 (refine) + fp32 (stage1)
// ---------------------------------------------------------------------------
__global__ __launch_bounds__(256) void cnorm_kernel(
    const float* __restrict__ cbs, double* __restrict__ cnorm,
    float* __restrict__ cnormF) {
  int gw = (blockIdx.x * blockDim.x + threadIdx.x) >> 6;
  int lane = threadIdx.x & 63;
  if (gw >= NL * KC) return;
  const float* row = cbs + (size_t)gw * CB;
  double s = 0.0;
  for (int i = lane; i < CB; i += 64) {
    double v = (double)row[i];
    s += v * v;
  }
#pragma unroll
  for (int off = 32; off > 0; off >>= 1)
    s += __shfl_down(s, off, 64);
  if (lane == 0) { cnorm[gw] = s; cnormF[gw] = (float)s; }
}

// ---------------------------------------------------------------------------
// Encoder GEMM: R = X @ W + b, fp64 accumulation.
// 128x64 tile, 4x8 per thread (32 fp64 acc -> ~110 VGPR), 4 blocks/CU.
// Per-element k-order identical to R5 -> bitwise same R.
// ---------------------------------------------------------------------------
__global__ __launch_bounds__(256, 4) void enc_gemm(
    const float* __restrict__ X, const float* __restrict__ W,
    const float* __restrict__ bias, float* __restrict__ R,
    unsigned short* __restrict__ Rhi, unsigned short* __restrict__ Rlo) {
  __shared__ float As[16][128];  // [kk][m], 8KB
  __shared__ float Bs[16][68];   // [kk][n] + pad, ~4.25KB
  int tid = threadIdx.x;
  int tx = tid & 7, ty = tid >> 3;  // 8 col-groups x 32 row-groups
  int g = blockIdx.x;
  int rb = (g & 7) + ((g >> 6) << 3);  // 8 col-blocks of rb share an XCD
  int cb8 = (g >> 3) & 7;
  int row0 = rb * 128, col0 = cb8 * 64;

  int sr = tid >> 1, skb = (tid & 1) * 8;   // A staging: row, k-base
  int bk = tid >> 4, bcc = (tid & 15) * 4;  // B staging: kk, col

  double acc[4][8] = {};
  for (int k0 = 0; k0 < DIN; k0 += 16) {
    float4 a0 = *(const float4*)(X + (size_t)(row0 + sr) * DIN + k0 + skb);
    float4 a1 = *(const float4*)(X + (size_t)(row0 + sr) * DIN + k0 + skb + 4);
    float4 b0 = *(const float4*)(W + (size_t)(k0 + bk) * CB + col0 + bcc);
    __syncthreads();  // previous iteration's LDS reads done
    As[skb + 0][sr] = a0.x; As[skb + 1][sr] = a0.y;
    As[skb + 2][sr] = a0.z; As[skb + 3][sr] = a0.w;
    As[skb + 4][sr] = a1.x; As[skb + 5][sr] = a1.y;
    As[skb + 6][sr] = a1.z; As[skb + 7][sr] = a1.w;
    *(float4*)&Bs[bk][bcc] = b0;
    __syncthreads();
#pragma unroll
    for (int kk = 0; kk < 16; ++kk) {
      float4 av = *(const float4*)&As[kk][ty * 4];
      float4 bv0 = *(const float4*)&Bs[kk][tx * 8];
      float4 bv1 = *(const float4*)&Bs[kk][tx * 8 + 4];
      double a[4] = {(double)av.x, (double)av.y, (double)av.z, (double)av.w};
      double b[8] = {(double)bv0.x, (double)bv0.y, (double)bv0.z, (double)bv0.w,
                     (double)bv1.x, (double)bv1.y, (double)bv1.z, (double)bv1.w};
#pragma unroll
      for (int i = 0; i < 4; ++i)
#pragma unroll
        for (int j = 0; j < 8; ++j)
          acc[i][j] += a[i] * b[j];
    }
  }

  double bb[8];
#pragma unroll
  for (int j = 0; j < 8; ++j) bb[j] = (double)bias[col0 + tx * 8 + j];
#pragma unroll
  for (int i = 0; i < 4; ++i) {
    int r = row0 + ty * 4 + i;
    int c0 = col0 + tx * 8;
    float vr[8];
    unsigned short vh[8], vl[8];
#pragma unroll
    for (int j = 0; j < 8; ++j) {
      float v = (float)(acc[i][j] + bb[j]);
      vr[j] = v;
      vh[j] = f2bf(v);
      vl[j] = f2bf(v - bf2f(vh[j]));
    }
    size_t o = (size_t)r * CB + c0;
    *(float4*)(R + o) = make_float4(vr[0], vr[1], vr[2], vr[3]);
    *(float4*)(R + o + 4) = make_float4(vr[4], vr[5], vr[6], vr[7]);
    size_t so = staged_off(r, c0);  // c0 aligned 8 -> j=0..7 contiguous
    *(ushort4*)(Rhi + so) = make_ushort4(vh[0], vh[1], vh[2], vh[3]);
    *(ushort4*)(Rhi + so + 4) = make_ushort4(vh[4], vh[5], vh[6], vh[7]);
    *(ushort4*)(Rlo + so) = make_ushort4(vl[0], vl[1], vl[2], vl[3]);
    *(ushort4*)(Rlo + so + 4) = make_ushort4(vl[4], vl[5], vl[6], vl[7]);
  }
}

// ---------------------------------------------------------------------------
// Stage 1: 3-term bf16-split MFMA distance GEMM, 128x128 tile, BK=32.
// Staged-layout inputs: every global_load_lds is 1KB contiguous global ->
// 1KB contiguous LDS; frag reads are lane-linear ds_read_b128.
// ---------------------------------------------------------------------------
__global__ __launch_bounds__(256) void vq_stage1(
    const unsigned short* __restrict__ Rhi, const unsigned short* __restrict__ Rlo,
    const unsigned short* __restrict__ Chi, const unsigned short* __restrict__ Clo,
    const float* __restrict__ cnormF, float4* __restrict__ cand) {
  __shared__ __align__(16) char lds[32768];  // Ahi,Alo,Bhi,Blo: 8KB each
  __shared__ float4 sRed[128][2];
  int tid = threadIdx.x;
  int wave = tid >> 6, lane = tid & 63;
  int wm = wave >> 1, wn = wave & 1;
  int q = lane >> 4, l15 = lane & 15;
  int g = blockIdx.x;
  int rb = (g & 7) + ((g >> 6) << 3);  // 8 col-blocks of rb share an XCD
  int cbk = (g >> 3) & 7;
  int row0 = rb * 128, n0 = cbk * 128;

  f32x4 acc[4][4];
#pragma unroll
  for (int i = 0; i < 4; ++i)
#pragma unroll
    for (int j = 0; j < 4; ++j)
      acc[i][j] = (f32x4){0.f, 0.f, 0.f, 0.f};

  // wave-uniform staging source (wave 0:Rhi 1:Rlo 2:Chi 3:Clo)
  const unsigned short* gsrc;
  int gbase;  // 16-row group index
  if (wave == 0)      { gsrc = Rhi; gbase = row0 >> 4; }
  else if (wave == 1) { gsrc = Rlo; gbase = row0 >> 4; }
  else if (wave == 2) { gsrc = Chi; gbase = n0 >> 4; }
  else                { gsrc = Clo; gbase = n0 >> 4; }
  const unsigned short* gw = gsrc + (size_t)gbase * 8192 + lane * 8;
  char* lbase = lds + wave * 8192;

  for (int kt = 0; kt < 16; ++kt) {
    __syncthreads();
#pragma unroll
    for (int s = 0; s < 8; ++s) {
      __builtin_amdgcn_global_load_lds(
          (const __attribute__((address_space(1))) void*)(gw + (size_t)s * 8192 + kt * 512),
          (__attribute__((address_space(3))) void*)(lbase + s * 1024), 16, 0, 0);
    }
    __syncthreads();

    short8 ahi[4], alo[4];
#pragma unroll
    for (int ti = 0; ti < 4; ++ti) {
      int pl = (wm * 4 + ti) * 1024 + lane * 16;
      ahi[ti] = *(const short8*)(lds + pl);
      alo[ti] = *(const short8*)(lds + 8192 + pl);
    }
#pragma unroll
    for (int tj = 0; tj < 4; ++tj) {
      int pl = (wn * 4 + tj) * 1024 + lane * 16;
      short8 bhi = *(const short8*)(lds + 16384 + pl);
      short8 blo = *(const short8*)(lds + 24576 + pl);
      // per-acc order stays hh,hl,lh per kt (bitwise identical to R5)
#pragma unroll
      for (int ti = 0; ti < 4; ++ti)
        acc[ti][tj] = __builtin_amdgcn_mfma_f32_16x16x32_bf16(ahi[ti], bhi, acc[ti][tj], 0, 0, 0);
#pragma unroll
      for (int ti = 0; ti < 4; ++ti)
        acc[ti][tj] = __builtin_amdgcn_mfma_f32_16x16x32_bf16(ahi[ti], blo, acc[ti][tj], 0, 0, 0);
#pragma unroll
      for (int ti = 0; ti < 4; ++ti)
        acc[ti][tj] = __builtin_amdgcn_mfma_f32_16x16x32_bf16(alo[ti], bhi, acc[ti][tj], 0, 0, 0);
    }
  }

  // Epilogue: d = cn - 2S; per-row top-2 over this wave's 64 cols, then
  // cross-wn merge via sRed.
  float cn[4]; int coln[4];
#pragma unroll
  for (int tj = 0; tj < 4; ++tj) {
    coln[tj] = n0 + wn * 64 + tj * 16 + l15;
    cn[tj] = cnormF[coln[tj]];
  }
#pragma unroll
  for (int ti = 0; ti < 4; ++ti) {
#pragma unroll
    for (int r = 0; r < 4; ++r) {
      float m1 = FLT_MAX, m2 = FLT_MAX;
      int i1 = INT_MAX, i2 = INT_MAX;
#pragma unroll
      for (int tj = 0; tj < 4; ++tj) {
        float v = cn[tj] - 2.0f * acc[ti][tj][r];
        int ix = coln[tj];
        if (v < m1 || (v == m1 && ix < i1)) {
          m2 = m1; i2 = i1; m1 = v; i1 = ix;
        } else if (v < m2 || (v == m2 && ix < i2)) {
          m2 = v; i2 = ix;
        }
      }
#pragma unroll
      for (int mask = 1; mask <= 8; mask <<= 1) {
        float om1 = __shfl_xor(m1, mask, 64);
        int   oi1 = __shfl_xor(i1, mask, 64);
        float om2 = __shfl_xor(m2, mask, 64);
        int   oi2 = __shfl_xor(i2, mask, 64);
        if (om1 < m1 || (om1 == m1 && oi1 < i1)) {
          m2 = m1; i2 = i1; m1 = om1; i1 = oi1;
        } else if (om1 < m2 || (om1 == m2 && oi1 < i2)) {
          m2 = om1; i2 = oi1;
        }
        if (om2 < m1 || (om2 == m1 && oi2 < i1)) {
          m2 = m1; i2 = i1; m1 = om2; i1 = oi2;
        } else if (om2 < m2 || (om2 == m2 && oi2 < i2)) {
          m2 = om2; i2 = oi2;
        }
      }
      if (l15 == 0) {
        int rit = wm * 64 + ti * 16 + q * 4 + r;
        sRed[rit][wn] =
            make_float4(m1, __int_as_float(i1), m2, __int_as_float(i2));
      }
    }
  }
  __syncthreads();

  if (tid < 128) {
    float4 e0 = sRed[tid][0], e1 = sRed[tid][1];
    float v[4] = {e0.x, e0.z, e1.x, e1.z};
    int ix[4] = {__float_as_int(e0.y), __float_as_int(e0.w),
                 __float_as_int(e1.y), __float_as_int(e1.w)};
    float M1 = FLT_MAX, M2 = FLT_MAX;
    int I1 = INT_MAX, I2 = INT_MAX;
#pragma unroll
    for (int p = 0; p < 4; ++p) {
      if (v[p] < M1 || (v[p] == M1 && ix[p] < I1)) {
        M2 = M1; I2 = I1; M1 = v[p]; I1 = ix[p];
      } else if (v[p] < M2 || (v[p] == M2 && ix[p] < I2)) {
        M2 = v[p]; I2 = ix[p];
      }
    }
    cand[(size_t)(row0 + tid) * 8 + cbk] =
        make_float4(M1, __int_as_float(I1), M2, __int_as_float(I2));
  }
}

// ---------------------------------------------------------------------------
// Stage 2: combine 8 chunk top-2s; fp64-refine near-ties (vs fp32 R);
// write id; update residual (row-major R) + staged-layout Rhi/Rlo.
// ---------------------------------------------------------------------------
__global__ __launch_bounds__(256) void vq_refine(
    const float* __restrict__ cb, const double* __restrict__ cnorm,
    const float4* __restrict__ cand, float* __restrict__ R,
    unsigned short* __restrict__ Rhi, unsigned short* __restrict__ Rlo,
    float* __restrict__ idsF, int layer) {
  __shared__ int sIdx[64][16];
  __shared__ int sCnt[64];
  __shared__ int sBest[64];

  int tid = threadIdx.x;
  int row0 = blockIdx.x * 64;

  if (tid < 64) {
    int row = row0 + tid;
    float v[16]; int ix[16];
#pragma unroll
    for (int c = 0; c < 8; ++c) {
      float4 e = cand[(size_t)row * 8 + c];
      v[2 * c] = e.x;     ix[2 * c] = __float_as_int(e.y);
      v[2 * c + 1] = e.z; ix[2 * c + 1] = __float_as_int(e.w);
    }
    float M = FLT_MAX; int I = INT_MAX;
#pragma unroll
    for (int p = 0; p < 16; ++p)
      if (v[p] < M || (v[p] == M && ix[p] < I)) { M = v[p]; I = ix[p]; }
    int cnt = 0;
#pragma unroll
    for (int p = 0; p < 16; ++p)
      if (v[p] < M + DELTA && cnt < 16) sIdx[tid][cnt++] = ix[p];
    sCnt[tid] = cnt;
    sBest[tid] = I;
  }
  __syncthreads();

  int wave = tid >> 6, lane = tid & 63;
  for (int r = wave * 16; r < wave * 16 + 16; ++r) {
    int cnt = sCnt[r];
    if (cnt < 2) continue;
    double bestD = 1e300; int bestI = INT_MAX;
    const float* rrow = R + (size_t)(row0 + r) * CB;
    for (int c = 0; c < cnt; ++c) {
      int idx = sIdx[r][c];
      const float* crow = cb + (size_t)idx * CB;
      double s = 0.0;
      for (int e = lane; e < CB; e += 64)
        s += (double)rrow[e] * (double)crow[e];
#pragma unroll
      for (int off = 32; off > 0; off >>= 1)
        s += __shfl_xor(s, off, 64);
      double d = cnorm[idx] - 2.0 * s;
      if (d < bestD || (d == bestD && idx < bestI)) { bestD = d; bestI = idx; }
    }
    if (lane == 0) sBest[r] = bestI;
  }
  __syncthreads();

  if (tid < 64)
    idsF[(size_t)(row0 + tid) * NL + layer] = (float)sBest[tid];

  // residual update: 4 elements per thread per iter
  for (int it = tid; it < 64 * (CB / 4); it += 256) {
    int r = it >> 7, dq = (it & 127) * 4;
    int row = row0 + r;
    size_t o = (size_t)row * CB + dq;
    float4 rv = *(const float4*)(R + o);
    const float* crow = cb + (size_t)sBest[r] * CB + dq;
    float nv[4] = {rv.x - crow[0], rv.y - crow[1], rv.z - crow[2], rv.w - crow[3]};
    *(float4*)(R + o) = make_float4(nv[0], nv[1], nv[2], nv[3]);
    unsigned short vh[4], vl[4];
#pragma unroll
    for (int j = 0; j < 4; ++j) {
      vh[j] = f2bf(nv[j]);
      vl[j] = f2bf(nv[j] - bf2f(vh[j]));
    }
    size_t so = staged_off(row, dq);  // dq aligned 4 -> one chunk
    *(ushort4*)(Rhi + so) = make_ushort4(vh[0], vh[1], vh[2], vh[3]);
    *(ushort4*)(Rlo + so) = make_ushort4(vl[0], vl[1], vl[2], vl[3]);
  }
}

// ---------------------------------------------------------------------------
// recon[b][j] = dec_b[j] + sum_l ids[b][l] * dec_W[l][j]
// ---------------------------------------------------------------------------
__global__ __launch_bounds__(256) void recon_kernel(
    const float* __restrict__ idsF, const float* __restrict__ decW,
    const float* __restrict__ decb, float* __restrict__ recon) {
  int g = blockIdx.x * 256 + threadIdx.x;
  int b = g >> 9, j = g & (CB - 1);
  float s = decb[j];
#pragma unroll
  for (int l = 0; l < NL; ++l)
    s += idsF[(size_t)b * NL + l] * decW[l * CB + j];
  recon[g] = s;
}

extern "C" void kernel_launch(void* const* d_in, const int* in_sizes, int n_in,
                              void* d_out, int out_size, void* d_ws, size_t ws_size,
                              hipStream_t stream) {
  const float* X    = (const float*)d_in[0];
  const float* encW = (const float*)d_in[1];
  const float* encb = (const float*)d_in[2];
  const float* cbs  = (const float*)d_in[3];
  const float* decW = (const float*)d_in[4];
  const float* decb = (const float*)d_in[5];

  float* out = (float*)d_out;
  float* recon = out;
  float* idsF = out + (size_t)BB * CB;

  char* ws = (char*)d_ws;
  float* R = (float*)ws;                 ws += (size_t)BB * CB * 4;        // 32 MB
  unsigned short* Rhi = (unsigned short*)ws; ws += (size_t)BB * CB * 2;    // 16 MB
  unsigned short* Rlo = (unsigned short*)ws; ws += (size_t)BB * CB * 2;    // 16 MB
  unsigned short* Chi = (unsigned short*)ws; ws += (size_t)NL * KC * CB * 2; // 4 MB
  unsigned short* Clo = (unsigned short*)ws; ws += (size_t)NL * KC * CB * 2; // 4 MB
  double* cnorm = (double*)ws;           ws += (size_t)NL * KC * 8;        // 32 KB
  float* cnormF = (float*)ws;            ws += (size_t)NL * KC * 4;        // 16 KB
  float4* cand = (float4*)ws;            // [BB][8] float4 = 2 MB

  cbsplit_kernel<<<(NL * KC * CB) / 1024, 256, 0, stream>>>(cbs, Chi, Clo);
  cnorm_kernel<<<(NL * KC) / 4, 256, 0, stream>>>(cbs, cnorm, cnormF);
  enc_gemm<<<(BB / 128) * (CB / 64), 256, 0, stream>>>(X, encW, encb, R, Rhi, Rlo);
  for (int l = 0; l < NL; ++l) {
    const float* cbl = cbs + (size_t)l * KC * CB;
    vq_stage1<<<(BB / 128) * 8, 256, 0, stream>>>(
        Rhi, Rlo, Chi + (size_t)l * KC * CB, Clo + (size_t)l * KC * CB,
        cnormF + (size_t)l * KC, cand);
    vq_refine<<<BB / 64, 256, 0, stream>>>(cbl, cnorm + (size_t)l * KC, cand,
                                           R, Rhi, Rlo, idsF, l);
  }
  recon_kernel<<<(BB * CB) / 256, 256, 0, stream>>>(idsF, decW, decb, recon);
}